// Round 3
// baseline (266.332 us; speedup 1.0000x reference)
//
#include <hip/hip_runtime.h>
#include <hip/hip_bf16.h>
#include <math.h>

#define Nn    512
#define CS    384
#define CZ    128
#define CH    16
#define Hh    12
#define PQ    4
#define PV    8
#define NCOL  1152   // 192*3 + 144*2 + 288
#define FIN   2112

#define W_C   0.23570226039551584f   // sqrt(2/(9*4))
#define W_L   0.5773502691896258f    // sqrt(1/3)

typedef unsigned short ushort_t;
typedef __attribute__((ext_vector_type(8))) short bf16x8;
typedef __attribute__((ext_vector_type(4))) float f32x4;

// ---------------- workspace layout (float offsets) ----------------
// sizes: P 589824 | mq/mk 6144 each | vpg 147456 | feat 1081344 |
//        log 3145728 | z16 16777216 (bf16 33.5M) | ekb/eqb 98304 each | wbf 1024
#define OFF_P      0u
#define OFF_MQ     589824u
#define OFF_MK     595968u
#define OFF_VPG    602112u
#define OFF_FEAT   749568u
#define OFF_LOG    1830912u     // logits -> a in place; later reused as K5 partials
#define OFF_Z16    4976640u     // ends 21753856
#define OFF_EKB    21753856u
#define OFF_EQB    21852160u
#define OFF_WBF    21950464u
// total = 21,951,488 floats = 87.8 MB

__device__ inline ushort_t f2bf(float f) {
  __hip_bfloat16 h = __float2bfloat16(f);
  return *reinterpret_cast<ushort_t*>(&h);
}

// ================= K1: projections  P = s_i @ [Wq|Wk|Wv|Wqp|Wkp|Wvp] =========
__global__ __launch_bounds__(384) void k_proj(
    const float* __restrict__ s, const float* __restrict__ Wq,
    const float* __restrict__ Wk, const float* __restrict__ Wv,
    const float* __restrict__ Wqp, const float* __restrict__ Wkp,
    const float* __restrict__ Wvp, float* __restrict__ P) {
  int col = blockIdx.x * 384 + threadIdx.x;       // 0..1151
  int i0  = blockIdx.y * 8;
  const float* base; int stride, off;
  if      (col < 192) { base = Wq;  stride = 192; off = col;       }
  else if (col < 384) { base = Wk;  stride = 192; off = col - 192; }
  else if (col < 576) { base = Wv;  stride = 192; off = col - 384; }
  else if (col < 720) { base = Wqp; stride = 144; off = col - 576; }
  else if (col < 864) { base = Wkp; stride = 144; off = col - 720; }
  else                { base = Wvp; stride = 288; off = col - 864; }
  float acc[8];
#pragma unroll
  for (int ii = 0; ii < 8; ++ii) acc[ii] = 0.f;
  const float* bp = base + off;
#pragma unroll 4
  for (int k = 0; k < CS; ++k) {
    float w = bp[k * stride];
#pragma unroll
    for (int ii = 0; ii < 8; ++ii) acc[ii] += w * s[(i0 + ii) * CS + k];
  }
#pragma unroll
  for (int ii = 0; ii < 8; ++ii) P[(size_t)(i0 + ii) * NCOL + col] = acc[ii];
}

// ===== K1b: rigid transforms -> eqb/ekb (bf16, padded 32), mq/mk, vp_g ======
__global__ __launch_bounds__(64) void k_prep(
    const float* __restrict__ P, const float* __restrict__ rot,
    const float* __restrict__ trans, const float* __restrict__ gamma,
    ushort_t* __restrict__ eqb, ushort_t* __restrict__ ekb,
    float* __restrict__ mq, float* __restrict__ mk, float* __restrict__ vpg) {
  int gid = blockIdx.x * 64 + threadIdx.x;        // < 6144
  int i = gid / Hh, h = gid % Hh;
  const float* Pi = P + (size_t)i * NCOL;
  float R[9], T[3];
#pragma unroll
  for (int m = 0; m < 9; ++m) R[m] = rot[i * 9 + m];
#pragma unroll
  for (int m = 0; m < 3; ++m) T[m] = trans[i * 3 + m];
  float cg = W_C * gamma[h];

  ushort_t* eq = eqb + (size_t)gid * 32;
  ushort_t* ek = ekb + (size_t)gid * 32;
#pragma unroll
  for (int d = 0; d < CH; ++d) eq[d] = f2bf(Pi[h * CH + d] * 0.25f);   // q/sqrt(16)
#pragma unroll
  for (int d = 0; d < CH; ++d) ek[d] = f2bf(Pi[192 + h * CH + d]);     // k
  float sq = 0.f, sk = 0.f;
#pragma unroll
  for (int p = 0; p < PQ; ++p) {
    float x = Pi[576 + h * 12 + p * 3 + 0];
    float y = Pi[576 + h * 12 + p * 3 + 1];
    float zc = Pi[576 + h * 12 + p * 3 + 2];
    float gx = R[0] * x + R[1] * y + R[2] * zc + T[0];
    float gy = R[3] * x + R[4] * y + R[5] * zc + T[1];
    float gz = R[6] * x + R[7] * y + R[8] * zc + T[2];
    eq[16 + p * 3 + 0] = f2bf(cg * gx);
    eq[16 + p * 3 + 1] = f2bf(cg * gy);
    eq[16 + p * 3 + 2] = f2bf(cg * gz);
    sq += gx * gx + gy * gy + gz * gz;
  }
#pragma unroll
  for (int p = 0; p < PQ; ++p) {
    float x = Pi[720 + h * 12 + p * 3 + 0];
    float y = Pi[720 + h * 12 + p * 3 + 1];
    float zc = Pi[720 + h * 12 + p * 3 + 2];
    float gx = R[0] * x + R[1] * y + R[2] * zc + T[0];
    float gy = R[3] * x + R[4] * y + R[5] * zc + T[1];
    float gz = R[6] * x + R[7] * y + R[8] * zc + T[2];
    ek[16 + p * 3 + 0] = f2bf(gx);
    ek[16 + p * 3 + 1] = f2bf(gy);
    ek[16 + p * 3 + 2] = f2bf(gz);
    sk += gx * gx + gy * gy + gz * gz;
  }
#pragma unroll
  for (int d = 28; d < 32; ++d) { eq[d] = 0; ek[d] = 0; }
  mq[gid] = -0.5f * cg * sq;
  mk[gid] = -0.5f * cg * sk;
#pragma unroll
  for (int p = 0; p < PV; ++p) {
    float x = Pi[864 + h * 24 + p * 3 + 0];
    float y = Pi[864 + h * 24 + p * 3 + 1];
    float zc = Pi[864 + h * 24 + p * 3 + 2];
    vpg[(size_t)i * 288 + h * 24 + p * 3 + 0] = R[0] * x + R[1] * y + R[2] * zc + T[0];
    vpg[(size_t)i * 288 + h * 24 + p * 3 + 1] = R[3] * x + R[4] * y + R[5] * zc + T[1];
    vpg[(size_t)i * 288 + h * 24 + p * 3 + 2] = R[6] * x + R[7] * y + R[8] * zc + T[2];
  }
}

// ===== K1c: Wb B-fragments (dense): wbf[kk][lane][e] for 16x16x32 MFMA ======
__global__ __launch_bounds__(256) void k_wbfrag(
    const float* __restrict__ Wb, ushort_t* __restrict__ wbf) {
  int t = threadIdx.x;            // 256 = 4 ksteps * 64 lanes
  int kk = t >> 6, l = t & 63;
  int h = l & 15, lk = l >> 4;
#pragma unroll
  for (int e = 0; e < 8; ++e) {
    int c = kk * 32 + lk * 8 + e;                 // k-index = z channel
    wbf[t * 8 + e] = (h < Hh) ? f2bf(Wb[c * Hh + h]) : (ushort_t)0;
  }
}

// ======== K2: logits via MFMA; also emits z16 (bf16 copy of z) ==============
__global__ __launch_bounds__(256) void k_logits_mfma(
    const float* __restrict__ z, const ushort_t* __restrict__ eqb,
    const ushort_t* __restrict__ ekb, const ushort_t* __restrict__ wbf,
    const float* __restrict__ mq, const float* __restrict__ mk,
    ushort_t* __restrict__ z16, float* __restrict__ logits) {
  __shared__ ushort_t zt[64 * 128];                // 16 KB bf16 tile, xor-swizzled
  int i = blockIdx.y, j0 = blockIdx.x * 64;
  int tid = threadIdx.x;

  // ---- stage: z f32 -> bf16 -> LDS (swizzled) + z16 global (linear) ----
  const float4* zg = (const float4*)(z + ((size_t)i * Nn + j0) * CZ);
  ushort_t* z16o = z16 + ((size_t)i * Nn + j0) * CZ;
#pragma unroll
  for (int it = 0; it < 4; ++it) {
    int chunk = it * 256 + tid;                   // 0..1023 = row*16 + c8
    int row = chunk >> 4, c8 = chunk & 15;
    float4 a4 = zg[chunk * 2], b4 = zg[chunk * 2 + 1];
    bf16x8 p;
    p[0] = (short)f2bf(a4.x); p[1] = (short)f2bf(a4.y);
    p[2] = (short)f2bf(a4.z); p[3] = (short)f2bf(a4.w);
    p[4] = (short)f2bf(b4.x); p[5] = (short)f2bf(b4.y);
    p[6] = (short)f2bf(b4.z); p[7] = (short)f2bf(b4.w);
    *(bf16x8*)&zt[row * 128 + ((c8 ^ (row & 7)) << 3)] = p;   // swizzled
    *(bf16x8*)(z16o + chunk * 8) = p;                          // linear
  }
  __syncthreads();

  // ---- MFMA: each wave owns 16 j-rows ----
  int l = tid & 63, w = tid >> 6;
  int lrow = l & 15, lk = l >> 4;                 // A-row / B-col, k-subblock
  int row = w * 16 + lrow;                        // tile-local j
  int j = j0 + row;

  f32x4 acc = {0.f, 0.f, 0.f, 0.f};
  bf16x8 zer;
#pragma unroll
  for (int e = 0; e < 8; ++e) zer[e] = 0;

  // z @ Wb : 4 K-steps of 32 channels
#pragma unroll
  for (int kk = 0; kk < 4; ++kk) {
    int c8 = kk * 4 + lk;
    bf16x8 a = *(const bf16x8*)&zt[row * 128 + ((c8 ^ (row & 7)) << 3)];
    bf16x8 b = *(const bf16x8*)&wbf[(kk * 64 + l) * 8];
    acc = __builtin_amdgcn_mfma_f32_16x16x32_bf16(a, b, acc, 0, 0, 0);
  }
  // ext part: 12 block-diagonal K-steps (head hp occupies k=hp*32..+31)
#pragma unroll
  for (int hp = 0; hp < Hh; ++hp) {
    bf16x8 a = *(const bf16x8*)&ekb[((size_t)j * Hh + hp) * 32 + lk * 8];
    bf16x8 bq = *(const bf16x8*)&eqb[((size_t)i * Hh + hp) * 32 + lk * 8];
    bf16x8 b = (lrow == hp) ? bq : zer;
    acc = __builtin_amdgcn_mfma_f32_16x16x32_bf16(a, b, acc, 0, 0, 0);
  }

  // ---- epilogue: C/D layout col=lane&15, row=(lane>>4)*4+r ----
  int h = lrow;                                   // output head col
  if (h < Hh) {
    float mqv = mq[i * Hh + h];
    int jr = j0 + w * 16 + lk * 4;
    float4 o;
    o.x = W_L * (acc[0] + mqv + mk[(jr + 0) * Hh + h]);
    o.y = W_L * (acc[1] + mqv + mk[(jr + 1) * Hh + h]);
    o.z = W_L * (acc[2] + mqv + mk[(jr + 2) * Hh + h]);
    o.w = W_L * (acc[3] + mqv + mk[(jr + 3) * Hh + h]);
    *(float4*)(logits + ((size_t)i * Hh + h) * Nn + jr) = o;
  }
}

// ================= K3: softmax over j, in place ==============================
__global__ __launch_bounds__(128) void k_softmax(float* __restrict__ logits) {
  int row = blockIdx.x;                            // i*12+h
  int tid = threadIdx.x;
  float4* rp = (float4*)(logits + (size_t)row * Nn);
  float4 v = rp[tid];
  float m = fmaxf(fmaxf(v.x, v.y), fmaxf(v.z, v.w));
#pragma unroll
  for (int k = 32; k >= 1; k >>= 1) m = fmaxf(m, __shfl_xor(m, k));
  __shared__ float red[2][2];
  int wave = tid >> 6, lane = tid & 63;
  if (lane == 0) red[0][wave] = m;
  __syncthreads();
  m = fmaxf(red[0][0], red[0][1]);
  float4 e;
  e.x = __expf(v.x - m); e.y = __expf(v.y - m);
  e.z = __expf(v.z - m); e.w = __expf(v.w - m);
  float s = e.x + e.y + e.z + e.w;
#pragma unroll
  for (int k = 32; k >= 1; k >>= 1) s += __shfl_xor(s, k);
  if (lane == 0) red[1][wave] = s;
  __syncthreads();
  s = red[1][0] + red[1][1];
  float r = 1.f / s;
  e.x *= r; e.y *= r; e.z *= r; e.w *= r;
  rp[tid] = e;
}

// ===== K4: per-i attention apply: o_pair (bf16 z), o_sc, o_pt+norm -> feat ===
__global__ __launch_bounds__(384) void k_attend(
    const ushort_t* __restrict__ z16, const float* __restrict__ a,
    const float* __restrict__ P, const float* __restrict__ vpg,
    const float* __restrict__ rot, const float* __restrict__ trans,
    float* __restrict__ feat) {
  int i = blockIdx.x, tid = threadIdx.x;
  float* Fi = feat + (size_t)i * FIN;
  __shared__ float as[Hh * Nn];                    // 24 KB: a rows for this i
  __shared__ float optg[288];

  {
    const float4* ag = (const float4*)(a + (size_t)i * Hh * Nn);
    float4* as4 = (float4*)as;
#pragma unroll
    for (int t = 0; t < 4; ++t) as4[t * 384 + tid] = ag[t * 384 + tid];
  }
  __syncthreads();

  // phase A: o_pair[h][c] — 6 waves x 2 heads, dword = 2 bf16 channels
  {
    int wv = tid >> 6, lane = tid & 63;
    const unsigned int* zrow = (const unsigned int*)(z16 + (size_t)i * Nn * CZ);
    const float* a0 = as + (wv * 2 + 0) * Nn;
    const float* a1 = as + (wv * 2 + 1) * Nn;
    float s00 = 0.f, s01 = 0.f, s10 = 0.f, s11 = 0.f;
#pragma unroll 4
    for (int j = 0; j < Nn; ++j) {
      unsigned int zz = zrow[j * 64 + lane];
      float zl = __uint_as_float(zz << 16);
      float zh = __uint_as_float(zz & 0xffff0000u);
      float w0 = a0[j], w1 = a1[j];
      s00 += zl * w0; s01 += zh * w0;
      s10 += zl * w1; s11 += zh * w1;
    }
    Fi[(wv * 2 + 0) * CZ + lane * 2 + 0] = s00;
    Fi[(wv * 2 + 0) * CZ + lane * 2 + 1] = s01;
    Fi[(wv * 2 + 1) * CZ + lane * 2 + 0] = s10;
    Fi[(wv * 2 + 1) * CZ + lane * 2 + 1] = s11;
  }

  // phase B: o_sc (192 items) + o_pt_g (288 items) over 384 threads
  {
    if (tid < 192) {
      int h = tid >> 4;
      const float* ar = as + h * Nn;
      float acc = 0.f;
#pragma unroll 4
      for (int j = 0; j < Nn; ++j)
        acc += ar[j] * P[(size_t)j * NCOL + 384 + tid];
      Fi[1536 + tid] = acc;
    } else {
      int t2 = tid - 192;                          // 0..191
      int h = t2 / 24;
      const float* ar = as + h * Nn;
      float acc = 0.f;
#pragma unroll 4
      for (int j = 0; j < Nn; ++j)
        acc += ar[j] * vpg[(size_t)j * 288 + t2];
      optg[t2] = acc;
    }
    if (tid < 96) {
      int t2 = tid + 192;                          // 192..287
      int h = t2 / 24;
      const float* ar = as + h * Nn;
      float acc = 0.f;
#pragma unroll 4
      for (int j = 0; j < Nn; ++j)
        acc += ar[j] * vpg[(size_t)j * 288 + t2];
      optg[t2] = acc;
    }
  }
  __syncthreads();

  // phase C: invert-apply + norm
  if (tid < 96) {
    int h = tid >> 3, p = tid & 7;
    float g0 = optg[h * 24 + p * 3 + 0] - trans[i * 3 + 0];
    float g1 = optg[h * 24 + p * 3 + 1] - trans[i * 3 + 1];
    float g2 = optg[h * 24 + p * 3 + 2] - trans[i * 3 + 2];
    const float* R = rot + i * 9;
    float ss = 0.f;
#pragma unroll
    for (int nn2 = 0; nn2 < 3; ++nn2) {
      float o = R[nn2] * g0 + R[3 + nn2] * g1 + R[6 + nn2] * g2;   // R^T (g - t)
      Fi[1728 + h * 24 + p * 3 + nn2] = o;
      ss += o * o;
    }
    Fi[2016 + h * 8 + p] = sqrtf(ss + 1e-12f);
  }
}

// ============ K5a: out partials  part[fs][i][o] = feat[f-slice] @ Wf ========
__global__ __launch_bounds__(384) void k_out_partial(
    const float* __restrict__ feat, const float* __restrict__ Wf,
    float* __restrict__ part) {
  int fs = blockIdx.x;                     // 0..7 (f-slice of 264)
  int i0 = blockIdx.y * 8;
  int o = threadIdx.x;                     // 0..383
  float acc[8];
#pragma unroll
  for (int ii = 0; ii < 8; ++ii) acc[ii] = 0.f;
  int f0 = fs * 264;
#pragma unroll 4
  for (int f = f0; f < f0 + 264; ++f) {
    float w = Wf[(size_t)f * CS + o];
#pragma unroll
    for (int ii = 0; ii < 8; ++ii) acc[ii] += w * feat[(size_t)(i0 + ii) * FIN + f];
  }
#pragma unroll
  for (int ii = 0; ii < 8; ++ii)
    part[((size_t)fs * Nn + i0 + ii) * CS + o] = acc[ii];
}

// ============ K5b: reduce partials + bias -> out ============================
__global__ __launch_bounds__(256) void k_out_reduce(
    const float* __restrict__ part, const float* __restrict__ bf,
    float* __restrict__ out) {
  int idx = blockIdx.x * 256 + threadIdx.x;        // < 512*384
  float s = bf[idx % CS];
#pragma unroll
  for (int fs = 0; fs < 8; ++fs) s += part[(size_t)fs * (Nn * CS) + idx];
  out[idx] = s;
}

// ============================ launcher ======================================
extern "C" void kernel_launch(void* const* d_in, const int* in_sizes, int n_in,
                              void* d_out, int out_size, void* d_ws, size_t ws_size,
                              hipStream_t stream) {
  const float* s_i   = (const float*)d_in[0];
  const float* z_ij  = (const float*)d_in[1];
  const float* rot   = (const float*)d_in[2];
  const float* trans = (const float*)d_in[3];
  const float* Wq    = (const float*)d_in[4];
  const float* Wk    = (const float*)d_in[5];
  const float* Wv    = (const float*)d_in[6];
  const float* Wqp   = (const float*)d_in[7];
  const float* Wkp   = (const float*)d_in[8];
  const float* Wvp   = (const float*)d_in[9];
  const float* Wb    = (const float*)d_in[10];
  const float* gamma = (const float*)d_in[11];
  const float* Wf    = (const float*)d_in[12];
  const float* bf    = (const float*)d_in[13];
  float* out = (float*)d_out;

  float* w = (float*)d_ws;
  float*    P    = w + OFF_P;
  float*    mq   = w + OFF_MQ;
  float*    mk   = w + OFF_MK;
  float*    vpg  = w + OFF_VPG;
  float*    feat = w + OFF_FEAT;
  float*    lg   = w + OFF_LOG;     // logits -> a (in place) -> K5 partials
  ushort_t* z16  = (ushort_t*)(w + OFF_Z16);
  ushort_t* ekb  = (ushort_t*)(w + OFF_EKB);
  ushort_t* eqb  = (ushort_t*)(w + OFF_EQB);
  ushort_t* wbf  = (ushort_t*)(w + OFF_WBF);

  k_proj<<<dim3(3, 64), 384, 0, stream>>>(s_i, Wq, Wk, Wv, Wqp, Wkp, Wvp, P);
  k_prep<<<96, 64, 0, stream>>>(P, rot, trans, gamma, eqb, ekb, mq, mk, vpg);
  k_wbfrag<<<1, 256, 0, stream>>>(Wb, wbf);
  k_logits_mfma<<<dim3(8, 512), 256, 0, stream>>>(z_ij, eqb, ekb, wbf, mq, mk, z16, lg);
  k_softmax<<<6144, 128, 0, stream>>>(lg);
  k_attend<<<512, 384, 0, stream>>>(z16, lg, P, vpg, rot, trans, feat);
  k_out_partial<<<dim3(8, 64), 384, 0, stream>>>(feat, Wf, lg);   // reuse lg
  k_out_reduce<<<768, 256, 0, stream>>>(lg, bf, out);
}

// Round 4
// 190.691 us; speedup vs baseline: 1.3967x; 1.3967x over previous
//
#include <hip/hip_runtime.h>
#include <hip/hip_bf16.h>
#include <math.h>

#define Nn    512
#define CS    384
#define CZ    128
#define CH    16
#define Hh    12
#define PQ    4
#define PV    8
#define NCOL  1152   // 192*3 + 144*2 + 288
#define FIN   2112

#define W_C   0.23570226039551584f   // sqrt(2/(9*4))
#define W_L   0.5773502691896258f    // sqrt(1/3)

typedef unsigned short ushort_t;
typedef __attribute__((ext_vector_type(8))) short bf16x8;
typedef __attribute__((ext_vector_type(4))) float f32x4;

// ---------------- workspace layout (float offsets) ----------------
#define OFF_P      0u           // N x 1152 raw projections (f32)
#define OFF_MQ     589824u
#define OFF_MK     595968u
#define OFF_VT     602112u      // v16T  [192][512] bf16  (49152 floats)
#define OFF_VPT    651264u      // vpgT  [288][512] bf16  (73728 floats)
#define OFF_FEAT   749568u      // N x 2112 f32
#define OFF_LOG    1830912u     // (N*H + 4) x N f32 (padded; a in place; K5 partial reuse)
#define OFF_Z16    4978688u     // N*N*128 bf16 (16777216 float-equiv)
#define OFF_EKB    21755904u
#define OFF_EQB    21854208u
#define OFF_WBF    21952512u
// total = 21,953,536 floats = 87.8 MB

__device__ inline ushort_t f2bf(float f) {
  __hip_bfloat16 h = __float2bfloat16(f);
  return *reinterpret_cast<ushort_t*>(&h);
}

// ================= K1: projections  P = s_i @ [Wq|Wk|Wv|Wqp|Wkp|Wvp] =========
__global__ __launch_bounds__(384) void k_proj(
    const float* __restrict__ s, const float* __restrict__ Wq,
    const float* __restrict__ Wk, const float* __restrict__ Wv,
    const float* __restrict__ Wqp, const float* __restrict__ Wkp,
    const float* __restrict__ Wvp, float* __restrict__ P) {
  int col = blockIdx.x * 384 + threadIdx.x;       // 0..1151
  int i0  = blockIdx.y * 8;
  const float* base; int stride, off;
  if      (col < 192) { base = Wq;  stride = 192; off = col;       }
  else if (col < 384) { base = Wk;  stride = 192; off = col - 192; }
  else if (col < 576) { base = Wv;  stride = 192; off = col - 384; }
  else if (col < 720) { base = Wqp; stride = 144; off = col - 576; }
  else if (col < 864) { base = Wkp; stride = 144; off = col - 720; }
  else                { base = Wvp; stride = 288; off = col - 864; }
  float acc[8];
#pragma unroll
  for (int ii = 0; ii < 8; ++ii) acc[ii] = 0.f;
  const float* bp = base + off;
#pragma unroll 4
  for (int k = 0; k < CS; ++k) {
    float w = bp[k * stride];
#pragma unroll
    for (int ii = 0; ii < 8; ++ii) acc[ii] += w * s[(i0 + ii) * CS + k];
  }
#pragma unroll
  for (int ii = 0; ii < 8; ++ii) P[(size_t)(i0 + ii) * NCOL + col] = acc[ii];
}

// ===== K1b: rigid transforms -> eqb/ekb bf16, mq/mk, v16T, vpgT =============
__global__ __launch_bounds__(64) void k_prep(
    const float* __restrict__ P, const float* __restrict__ rot,
    const float* __restrict__ trans, const float* __restrict__ gamma,
    ushort_t* __restrict__ eqb, ushort_t* __restrict__ ekb,
    float* __restrict__ mq, float* __restrict__ mk,
    ushort_t* __restrict__ vT, ushort_t* __restrict__ vpT) {
  int gid = blockIdx.x * 64 + threadIdx.x;        // < 6144
  int i = gid / Hh, h = gid % Hh;
  const float* Pi = P + (size_t)i * NCOL;
  float R[9], T[3];
#pragma unroll
  for (int m = 0; m < 9; ++m) R[m] = rot[i * 9 + m];
#pragma unroll
  for (int m = 0; m < 3; ++m) T[m] = trans[i * 3 + m];
  float cg = W_C * gamma[h];

  ushort_t* eq = eqb + (size_t)gid * 32;
  ushort_t* ek = ekb + (size_t)gid * 32;
#pragma unroll
  for (int d = 0; d < CH; ++d) eq[d] = f2bf(Pi[h * CH + d] * 0.25f);   // q/sqrt(16)
#pragma unroll
  for (int d = 0; d < CH; ++d) ek[d] = f2bf(Pi[192 + h * CH + d]);     // k
  float sq = 0.f, sk = 0.f;
#pragma unroll
  for (int p = 0; p < PQ; ++p) {
    float x = Pi[576 + h * 12 + p * 3 + 0];
    float y = Pi[576 + h * 12 + p * 3 + 1];
    float zc = Pi[576 + h * 12 + p * 3 + 2];
    float gx = R[0] * x + R[1] * y + R[2] * zc + T[0];
    float gy = R[3] * x + R[4] * y + R[5] * zc + T[1];
    float gz = R[6] * x + R[7] * y + R[8] * zc + T[2];
    eq[16 + p * 3 + 0] = f2bf(cg * gx);
    eq[16 + p * 3 + 1] = f2bf(cg * gy);
    eq[16 + p * 3 + 2] = f2bf(cg * gz);
    sq += gx * gx + gy * gy + gz * gz;
  }
#pragma unroll
  for (int p = 0; p < PQ; ++p) {
    float x = Pi[720 + h * 12 + p * 3 + 0];
    float y = Pi[720 + h * 12 + p * 3 + 1];
    float zc = Pi[720 + h * 12 + p * 3 + 2];
    float gx = R[0] * x + R[1] * y + R[2] * zc + T[0];
    float gy = R[3] * x + R[4] * y + R[5] * zc + T[1];
    float gz = R[6] * x + R[7] * y + R[8] * zc + T[2];
    ek[16 + p * 3 + 0] = f2bf(gx);
    ek[16 + p * 3 + 1] = f2bf(gy);
    ek[16 + p * 3 + 2] = f2bf(gz);
    sk += gx * gx + gy * gy + gz * gz;
  }
#pragma unroll
  for (int d = 28; d < 32; ++d) { eq[d] = 0; ek[d] = 0; }
  mq[gid] = -0.5f * cg * sq;
  mk[gid] = -0.5f * cg * sk;

  // v (o_sc V): transposed bf16 [col=h*16+d][j=i]
#pragma unroll
  for (int d = 0; d < CH; ++d)
    vT[(size_t)(h * CH + d) * Nn + i] = f2bf(Pi[384 + h * CH + d]);
  // vp_g: transposed bf16 [col=h*24+p*3+x][j=i]
#pragma unroll
  for (int p = 0; p < PV; ++p) {
    float x = Pi[864 + h * 24 + p * 3 + 0];
    float y = Pi[864 + h * 24 + p * 3 + 1];
    float zc = Pi[864 + h * 24 + p * 3 + 2];
    vpT[(size_t)(h * 24 + p * 3 + 0) * Nn + i] = f2bf(R[0] * x + R[1] * y + R[2] * zc + T[0]);
    vpT[(size_t)(h * 24 + p * 3 + 1) * Nn + i] = f2bf(R[3] * x + R[4] * y + R[5] * zc + T[1]);
    vpT[(size_t)(h * 24 + p * 3 + 2) * Nn + i] = f2bf(R[6] * x + R[7] * y + R[8] * zc + T[2]);
  }
}

// ===== K1c: Wb B-fragments (dense): wbf[kk][lane][e] for 16x16x32 MFMA ======
__global__ __launch_bounds__(256) void k_wbfrag(
    const float* __restrict__ Wb, ushort_t* __restrict__ wbf) {
  int t = threadIdx.x;            // 256 = 4 ksteps * 64 lanes
  int kk = t >> 6, l = t & 63;
  int h = l & 15, lk = l >> 4;
#pragma unroll
  for (int e = 0; e < 8; ++e) {
    int c = kk * 32 + lk * 8 + e;                 // k-index = z channel
    wbf[t * 8 + e] = (h < Hh) ? f2bf(Wb[c * Hh + h]) : (ushort_t)0;
  }
}

// ======== K2: logits via MFMA; also emits z16 (bf16 copy of z) ==============
__global__ __launch_bounds__(256) void k_logits_mfma(
    const float* __restrict__ z, const ushort_t* __restrict__ eqb,
    const ushort_t* __restrict__ ekb, const ushort_t* __restrict__ wbf,
    const float* __restrict__ mq, const float* __restrict__ mk,
    ushort_t* __restrict__ z16, float* __restrict__ logits) {
  __shared__ ushort_t zt[64 * 128];                // 16 KB bf16 tile, xor-swizzled
  int i = blockIdx.y, j0 = blockIdx.x * 64;
  int tid = threadIdx.x;

  const float4* zg = (const float4*)(z + ((size_t)i * Nn + j0) * CZ);
  ushort_t* z16o = z16 + ((size_t)i * Nn + j0) * CZ;
#pragma unroll
  for (int it = 0; it < 4; ++it) {
    int chunk = it * 256 + tid;                   // 0..1023 = row*16 + c8
    int row = chunk >> 4, c8 = chunk & 15;
    float4 a4 = zg[chunk * 2], b4 = zg[chunk * 2 + 1];
    bf16x8 p;
    p[0] = (short)f2bf(a4.x); p[1] = (short)f2bf(a4.y);
    p[2] = (short)f2bf(a4.z); p[3] = (short)f2bf(a4.w);
    p[4] = (short)f2bf(b4.x); p[5] = (short)f2bf(b4.y);
    p[6] = (short)f2bf(b4.z); p[7] = (short)f2bf(b4.w);
    *(bf16x8*)&zt[row * 128 + ((c8 ^ (row & 7)) << 3)] = p;   // swizzled
    *(bf16x8*)(z16o + chunk * 8) = p;                          // linear
  }
  __syncthreads();

  int l = tid & 63, w = tid >> 6;
  int lrow = l & 15, lk = l >> 4;
  int row = w * 16 + lrow;
  int j = j0 + row;

  f32x4 acc = {0.f, 0.f, 0.f, 0.f};
  bf16x8 zer;
#pragma unroll
  for (int e = 0; e < 8; ++e) zer[e] = 0;

#pragma unroll
  for (int kk = 0; kk < 4; ++kk) {
    int c8 = kk * 4 + lk;
    bf16x8 a = *(const bf16x8*)&zt[row * 128 + ((c8 ^ (row & 7)) << 3)];
    bf16x8 b = *(const bf16x8*)&wbf[(kk * 64 + l) * 8];
    acc = __builtin_amdgcn_mfma_f32_16x16x32_bf16(a, b, acc, 0, 0, 0);
  }
#pragma unroll
  for (int hp = 0; hp < Hh; ++hp) {
    bf16x8 a = *(const bf16x8*)&ekb[((size_t)j * Hh + hp) * 32 + lk * 8];
    bf16x8 bq = *(const bf16x8*)&eqb[((size_t)i * Hh + hp) * 32 + lk * 8];
    bf16x8 b = (lrow == hp) ? bq : zer;
    acc = __builtin_amdgcn_mfma_f32_16x16x32_bf16(a, b, acc, 0, 0, 0);
  }

  int h = lrow;                                   // D col = head
  if (h < Hh) {
    float mqv = mq[i * Hh + h];
    int jr = j0 + w * 16 + lk * 4;
    float4 o;
    o.x = W_L * (acc[0] + mqv + mk[(jr + 0) * Hh + h]);
    o.y = W_L * (acc[1] + mqv + mk[(jr + 1) * Hh + h]);
    o.z = W_L * (acc[2] + mqv + mk[(jr + 2) * Hh + h]);
    o.w = W_L * (acc[3] + mqv + mk[(jr + 3) * Hh + h]);
    *(float4*)(logits + ((size_t)i * Hh + h) * Nn + jr) = o;
  }
}

// ================= K3: softmax over j, in place ==============================
__global__ __launch_bounds__(128) void k_softmax(float* __restrict__ logits) {
  int row = blockIdx.x;                            // i*12+h
  int tid = threadIdx.x;
  float4* rp = (float4*)(logits + (size_t)row * Nn);
  float4 v = rp[tid];
  float m = fmaxf(fmaxf(v.x, v.y), fmaxf(v.z, v.w));
#pragma unroll
  for (int k = 32; k >= 1; k >>= 1) m = fmaxf(m, __shfl_xor(m, k));
  __shared__ float red[2][2];
  int wave = tid >> 6, lane = tid & 63;
  if (lane == 0) red[0][wave] = m;
  __syncthreads();
  m = fmaxf(red[0][0], red[0][1]);
  float4 e;
  e.x = __expf(v.x - m); e.y = __expf(v.y - m);
  e.z = __expf(v.z - m); e.w = __expf(v.w - m);
  float s = e.x + e.y + e.z + e.w;
#pragma unroll
  for (int k = 32; k >= 1; k >>= 1) s += __shfl_xor(s, k);
  if (lane == 0) red[1][wave] = s;
  __syncthreads();
  s = red[1][0] + red[1][1];
  float r = 1.f / s;
  e.x *= r; e.y *= r; e.z *= r; e.w *= r;
  rp[tid] = e;
}

// ===== K4: attention apply via MFMA: block per i, 8 waves, 38 col-tiles =====
// out[h][col] = sum_j a[h][j] * V[j][col], V = [z16 (128) | v (192) | vpg (288)]
__global__ __launch_bounds__(512) void k_attend_mfma(
    const ushort_t* __restrict__ z16, const float* __restrict__ a,
    const ushort_t* __restrict__ vT, const ushort_t* __restrict__ vpT,
    const float* __restrict__ rot, const float* __restrict__ trans,
    float* __restrict__ feat) {
  __shared__ ushort_t zt[2][32 * CZ];              // double-buffered j-tile, 8KB each
  __shared__ float optg[288];
  int i = blockIdx.x, tid = threadIdx.x;
  int l = tid & 63, w = tid >> 6;                  // 8 waves
  int cl = l & 15, lk = l >> 4;
  float* Fi = feat + (size_t)i * FIN;

  // stage j-tile kk into buffer b: 512 chunks of 16B, one per thread
#define STAGE(kk, b) { \
    int j_ = tid >> 4, c0_ = (tid & 15) * 8; \
    *(bf16x8*)&zt[b][j_ * CZ + c0_] = \
      *(const bf16x8*)(z16 + (((size_t)i * Nn) + (kk) * 32 + j_) * CZ + c0_); }

  f32x4 acc[5];
#pragma unroll
  for (int n = 0; n < 5; ++n) acc[n] = (f32x4){0.f, 0.f, 0.f, 0.f};

  STAGE(0, 0);
  __syncthreads();

  const float* arow = a + (size_t)(i * Hh + cl) * Nn;   // A row = head cl (pad rows valid)

  for (int kk = 0; kk < 16; ++kk) {
    int cur = kk & 1;
    if (kk < 15) STAGE(kk + 1, cur ^ 1);

    // A-fragment: a[cl][kk*32 + lk*8 + e], f32 -> bf16
    const float* ap = arow + kk * 32 + lk * 8;
    float4 x0 = *(const float4*)ap, x1 = *(const float4*)(ap + 4);
    bf16x8 af;
    af[0] = (short)f2bf(x0.x); af[1] = (short)f2bf(x0.y);
    af[2] = (short)f2bf(x0.z); af[3] = (short)f2bf(x0.w);
    af[4] = (short)f2bf(x1.x); af[5] = (short)f2bf(x1.y);
    af[6] = (short)f2bf(x1.z); af[7] = (short)f2bf(x1.w);

#pragma unroll
    for (int n = 0; n < 5; ++n) {
      int t = w + n * 8;
      if (t < 38) {
        bf16x8 bf;
        if (t < 8) {                               // o_pair: transposed LDS reads
          const ushort_t* zr = &zt[cur][(lk * 8) * CZ + t * 16 + cl];
#pragma unroll
          for (int e = 0; e < 8; ++e) bf[e] = (short)zr[e * CZ];
        } else if (t < 20) {                       // o_sc: v16T global
          bf = *(const bf16x8*)(vT + (size_t)((t - 8) * 16 + cl) * Nn + kk * 32 + lk * 8);
        } else {                                   // o_pt: vpgT global
          bf = *(const bf16x8*)(vpT + (size_t)((t - 20) * 16 + cl) * Nn + kk * 32 + lk * 8);
        }
        acc[n] = __builtin_amdgcn_mfma_f32_16x16x32_bf16(af, bf, acc[n], 0, 0, 0);
      }
    }
    __syncthreads();
  }

  // ---- epilogue: D row = lk*4+r (head), D col = cl ----
#pragma unroll
  for (int n = 0; n < 5; ++n) {
    int t = w + n * 8;
    if (t < 38) {
      if (t < 8) {
        int c = t * 16 + cl;
#pragma unroll
        for (int r = 0; r < 4; ++r) {
          int h = lk * 4 + r;
          if (h < Hh) Fi[h * CZ + c] = acc[n][r];
        }
      } else if (t < 20) {
        int h = t - 8;
        if (lk == (h >> 2)) Fi[1536 + h * 16 + cl] = acc[n][h & 3];
      } else {
        int cp = (t - 20) * 16 + cl;
        int h = cp / 24;
        if (lk == (h >> 2)) optg[cp] = acc[n][h & 3];
      }
    }
  }
  __syncthreads();

  // invert-apply + norm
  if (tid < 96) {
    int h = tid >> 3, p = tid & 7;
    float g0 = optg[h * 24 + p * 3 + 0] - trans[i * 3 + 0];
    float g1 = optg[h * 24 + p * 3 + 1] - trans[i * 3 + 1];
    float g2 = optg[h * 24 + p * 3 + 2] - trans[i * 3 + 2];
    const float* R = rot + i * 9;
    float ss = 0.f;
#pragma unroll
    for (int nn2 = 0; nn2 < 3; ++nn2) {
      float o = R[nn2] * g0 + R[3 + nn2] * g1 + R[6 + nn2] * g2;   // R^T (g - t)
      Fi[1728 + h * 24 + p * 3 + nn2] = o;
      ss += o * o;
    }
    Fi[2016 + h * 8 + p] = sqrtf(ss + 1e-12f);
  }
#undef STAGE
}

// ============ K5a: out partials  part[fs][i][o] = feat[f-slice] @ Wf ========
__global__ __launch_bounds__(384) void k_out_partial(
    const float* __restrict__ feat, const float* __restrict__ Wf,
    float* __restrict__ part) {
  int fs = blockIdx.x;                     // 0..7 (f-slice of 264)
  int i0 = blockIdx.y * 8;
  int o = threadIdx.x;                     // 0..383
  float acc[8];
#pragma unroll
  for (int ii = 0; ii < 8; ++ii) acc[ii] = 0.f;
  int f0 = fs * 264;
#pragma unroll 4
  for (int f = f0; f < f0 + 264; ++f) {
    float w = Wf[(size_t)f * CS + o];
#pragma unroll
    for (int ii = 0; ii < 8; ++ii) acc[ii] += w * feat[(size_t)(i0 + ii) * FIN + f];
  }
#pragma unroll
  for (int ii = 0; ii < 8; ++ii)
    part[((size_t)fs * Nn + i0 + ii) * CS + o] = acc[ii];
}

// ============ K5b: reduce partials + bias -> out ============================
__global__ __launch_bounds__(256) void k_out_reduce(
    const float* __restrict__ part, const float* __restrict__ bf,
    float* __restrict__ out) {
  int idx = blockIdx.x * 256 + threadIdx.x;        // < 512*384
  float s = bf[idx % CS];
#pragma unroll
  for (int fs = 0; fs < 8; ++fs) s += part[(size_t)fs * (Nn * CS) + idx];
  out[idx] = s;
}

// ============================ launcher ======================================
extern "C" void kernel_launch(void* const* d_in, const int* in_sizes, int n_in,
                              void* d_out, int out_size, void* d_ws, size_t ws_size,
                              hipStream_t stream) {
  const float* s_i   = (const float*)d_in[0];
  const float* z_ij  = (const float*)d_in[1];
  const float* rot   = (const float*)d_in[2];
  const float* trans = (const float*)d_in[3];
  const float* Wq    = (const float*)d_in[4];
  const float* Wk    = (const float*)d_in[5];
  const float* Wv    = (const float*)d_in[6];
  const float* Wqp   = (const float*)d_in[7];
  const float* Wkp   = (const float*)d_in[8];
  const float* Wvp   = (const float*)d_in[9];
  const float* Wb    = (const float*)d_in[10];
  const float* gamma = (const float*)d_in[11];
  const float* Wf    = (const float*)d_in[12];
  const float* bf    = (const float*)d_in[13];
  float* out = (float*)d_out;

  float* w = (float*)d_ws;
  float*    P    = w + OFF_P;
  float*    mq   = w + OFF_MQ;
  float*    mk   = w + OFF_MK;
  ushort_t* vT   = (ushort_t*)(w + OFF_VT);
  ushort_t* vpT  = (ushort_t*)(w + OFF_VPT);
  float*    feat = w + OFF_FEAT;
  float*    lg   = w + OFF_LOG;     // logits -> a (in place) -> K5 partials
  ushort_t* z16  = (ushort_t*)(w + OFF_Z16);
  ushort_t* ekb  = (ushort_t*)(w + OFF_EKB);
  ushort_t* eqb  = (ushort_t*)(w + OFF_EQB);
  ushort_t* wbf  = (ushort_t*)(w + OFF_WBF);

  k_proj<<<dim3(3, 64), 384, 0, stream>>>(s_i, Wq, Wk, Wv, Wqp, Wkp, Wvp, P);
  k_prep<<<96, 64, 0, stream>>>(P, rot, trans, gamma, eqb, ekb, mq, mk, vT, vpT);
  k_wbfrag<<<1, 256, 0, stream>>>(Wb, wbf);
  k_logits_mfma<<<dim3(8, 512), 256, 0, stream>>>(z_ij, eqb, ekb, wbf, mq, mk, z16, lg);
  k_softmax<<<6144, 128, 0, stream>>>(lg);
  k_attend_mfma<<<512, 512, 0, stream>>>(z16, lg, vT, vpT, rot, trans, feat);
  k_out_partial<<<dim3(8, 64), 384, 0, stream>>>(feat, Wf, lg);   // reuse lg
  k_out_reduce<<<768, 256, 0, stream>>>(lg, bf, out);
}

// Round 5
// 184.060 us; speedup vs baseline: 1.4470x; 1.0360x over previous
//
#include <hip/hip_runtime.h>
#include <hip/hip_bf16.h>
#include <math.h>

#define Nn    512
#define CS    384
#define CZ    128
#define CH    16
#define Hh    12
#define PQ    4
#define PV    8
#define NCOL  1152   // 192*3 + 144*2 + 288
#define FIN   2112
#define JT    128    // j-tile for fused kernel

#define W_C   0.23570226039551584f   // sqrt(2/(9*4))
#define W_L   0.5773502691896258f    // sqrt(1/3)

typedef unsigned short ushort_t;
typedef __attribute__((ext_vector_type(8))) short bf16x8;
typedef __attribute__((ext_vector_type(4))) float f32x4;

// ---------------- workspace layout (float offsets) ----------------
#define OFF_P      0u           // N x 1152 raw projections (f32)
#define OFF_MQ     589824u      // (unused by fused kernel, kept)
#define OFF_MK     595968u
#define OFF_VT     602112u      // v16T  [192][512] bf16
#define OFF_VPT    651264u      // vpgT  [288][512] bf16
#define OFF_FEAT   749568u      // N x 2112 f32
#define OFF_LOG    1830912u     // K5 partials (8 x N x 384 f32)
#define OFF_EKB    21755904u
#define OFF_EQB    21854208u
#define OFF_WBF    21952512u

__device__ inline ushort_t f2bf(float f) {
  __hip_bfloat16 h = __float2bfloat16(f);
  return *reinterpret_cast<ushort_t*>(&h);
}
__device__ inline float bf2f(ushort_t u) {
  unsigned int x = ((unsigned int)u) << 16;
  return __uint_as_float(x);
}

// ================= K1: projections  P = s_i @ [Wq|Wk|Wv|Wqp|Wkp|Wvp] =========
__global__ __launch_bounds__(384) void k_proj(
    const float* __restrict__ s, const float* __restrict__ Wq,
    const float* __restrict__ Wk, const float* __restrict__ Wv,
    const float* __restrict__ Wqp, const float* __restrict__ Wkp,
    const float* __restrict__ Wvp, float* __restrict__ P) {
  int col = blockIdx.x * 384 + threadIdx.x;       // 0..1151
  int i0  = blockIdx.y * 8;
  const float* base; int stride, off;
  if      (col < 192) { base = Wq;  stride = 192; off = col;       }
  else if (col < 384) { base = Wk;  stride = 192; off = col - 192; }
  else if (col < 576) { base = Wv;  stride = 192; off = col - 384; }
  else if (col < 720) { base = Wqp; stride = 144; off = col - 576; }
  else if (col < 864) { base = Wkp; stride = 144; off = col - 720; }
  else                { base = Wvp; stride = 288; off = col - 864; }
  float acc[8];
#pragma unroll
  for (int ii = 0; ii < 8; ++ii) acc[ii] = 0.f;
  const float* bp = base + off;
#pragma unroll 4
  for (int k = 0; k < CS; ++k) {
    float w = bp[k * stride];
#pragma unroll
    for (int ii = 0; ii < 8; ++ii) acc[ii] += w * s[(i0 + ii) * CS + k];
  }
#pragma unroll
  for (int ii = 0; ii < 8; ++ii) P[(size_t)(i0 + ii) * NCOL + col] = acc[ii];
}

// ===== K1b: rigid transforms -> eqb/ekb bf16, mq/mk, v16T, vpgT =============
__global__ __launch_bounds__(64) void k_prep(
    const float* __restrict__ P, const float* __restrict__ rot,
    const float* __restrict__ trans, const float* __restrict__ gamma,
    ushort_t* __restrict__ eqb, ushort_t* __restrict__ ekb,
    float* __restrict__ mq, float* __restrict__ mk,
    ushort_t* __restrict__ vT, ushort_t* __restrict__ vpT) {
  int gid = blockIdx.x * 64 + threadIdx.x;        // < 6144
  int i = gid / Hh, h = gid % Hh;
  const float* Pi = P + (size_t)i * NCOL;
  float R[9], T[3];
#pragma unroll
  for (int m = 0; m < 9; ++m) R[m] = rot[i * 9 + m];
#pragma unroll
  for (int m = 0; m < 3; ++m) T[m] = trans[i * 3 + m];
  float cg = W_C * gamma[h];

  ushort_t* eq = eqb + (size_t)gid * 32;
  ushort_t* ek = ekb + (size_t)gid * 32;
#pragma unroll
  for (int d = 0; d < CH; ++d) eq[d] = f2bf(Pi[h * CH + d] * 0.25f);   // q/sqrt(16)
#pragma unroll
  for (int d = 0; d < CH; ++d) ek[d] = f2bf(Pi[192 + h * CH + d]);     // k
  float sq = 0.f, sk = 0.f;
#pragma unroll
  for (int p = 0; p < PQ; ++p) {
    float x = Pi[576 + h * 12 + p * 3 + 0];
    float y = Pi[576 + h * 12 + p * 3 + 1];
    float zc = Pi[576 + h * 12 + p * 3 + 2];
    float gx = R[0] * x + R[1] * y + R[2] * zc + T[0];
    float gy = R[3] * x + R[4] * y + R[5] * zc + T[1];
    float gz = R[6] * x + R[7] * y + R[8] * zc + T[2];
    eq[16 + p * 3 + 0] = f2bf(cg * gx);
    eq[16 + p * 3 + 1] = f2bf(cg * gy);
    eq[16 + p * 3 + 2] = f2bf(cg * gz);
    sq += gx * gx + gy * gy + gz * gz;
  }
#pragma unroll
  for (int p = 0; p < PQ; ++p) {
    float x = Pi[720 + h * 12 + p * 3 + 0];
    float y = Pi[720 + h * 12 + p * 3 + 1];
    float zc = Pi[720 + h * 12 + p * 3 + 2];
    float gx = R[0] * x + R[1] * y + R[2] * zc + T[0];
    float gy = R[3] * x + R[4] * y + R[5] * zc + T[1];
    float gz = R[6] * x + R[7] * y + R[8] * zc + T[2];
    ek[16 + p * 3 + 0] = f2bf(gx);
    ek[16 + p * 3 + 1] = f2bf(gy);
    ek[16 + p * 3 + 2] = f2bf(gz);
    sk += gx * gx + gy * gy + gz * gz;
  }
#pragma unroll
  for (int d = 28; d < 32; ++d) { eq[d] = 0; ek[d] = 0; }
  mq[gid] = -0.5f * cg * sq;
  mk[gid] = -0.5f * cg * sk;

#pragma unroll
  for (int d = 0; d < CH; ++d)
    vT[(size_t)(h * CH + d) * Nn + i] = f2bf(Pi[384 + h * CH + d]);
#pragma unroll
  for (int p = 0; p < PV; ++p) {
    float x = Pi[864 + h * 24 + p * 3 + 0];
    float y = Pi[864 + h * 24 + p * 3 + 1];
    float zc = Pi[864 + h * 24 + p * 3 + 2];
    vpT[(size_t)(h * 24 + p * 3 + 0) * Nn + i] = f2bf(R[0] * x + R[1] * y + R[2] * zc + T[0]);
    vpT[(size_t)(h * 24 + p * 3 + 1) * Nn + i] = f2bf(R[3] * x + R[4] * y + R[5] * zc + T[1]);
    vpT[(size_t)(h * 24 + p * 3 + 2) * Nn + i] = f2bf(R[6] * x + R[7] * y + R[8] * zc + T[2]);
  }
}

// ===== K1c: Wb B-fragments (dense): wbf[kk][lane][e] for 16x16x32 MFMA ======
__global__ __launch_bounds__(256) void k_wbfrag(
    const float* __restrict__ Wb, ushort_t* __restrict__ wbf) {
  int t = threadIdx.x;            // 256 = 4 ksteps * 64 lanes
  int kk = t >> 6, l = t & 63;
  int h = l & 15, lk = l >> 4;
#pragma unroll
  for (int e = 0; e < 8; ++e) {
    int c = kk * 32 + lk * 8 + e;
    wbf[t * 8 + e] = (h < Hh) ? f2bf(Wb[c * Hh + h]) : (ushort_t)0;
  }
}

// ======== K2: FUSED logits + online softmax + attend (flash), block per i ====
__global__ __launch_bounds__(512) void k_fused(
    const float* __restrict__ z, const ushort_t* __restrict__ eqb,
    const ushort_t* __restrict__ ekb, const ushort_t* __restrict__ wbf,
    const float* __restrict__ mk,
    const ushort_t* __restrict__ vT, const ushort_t* __restrict__ vpT,
    const float* __restrict__ rot, const float* __restrict__ trans,
    float* __restrict__ feat) {
  __shared__ ushort_t zt[JT * CZ];        // 32 KB bf16 z-tile, xor-swizzled
  __shared__ ushort_t pbuf[16 * 136];     // P tile bf16, padded stride
  __shared__ float red[8][16];            // per-wave reductions
  __shared__ float mbc[16], scbc[16], linv[16];
  __shared__ float optg[288];

  int i = blockIdx.x, tid = threadIdx.x;
  int l = tid & 63, w = tid >> 6;         // 8 waves
  int cl = l & 15, lk = l >> 4;
  float* Fi = feat + (size_t)i * FIN;
  const float* zbase = z + (size_t)i * Nn * CZ;

  float m_run = -1e30f, l_run = 0.f;      // live in wave0 lanes 0..15

  f32x4 acc[5];
#pragma unroll
  for (int n = 0; n < 5; ++n) acc[n] = (f32x4){0.f, 0.f, 0.f, 0.f};
  bf16x8 zer;
#pragma unroll
  for (int e = 0; e < 8; ++e) zer[e] = 0;

  for (int t4 = 0; t4 < 4; ++t4) {
    int j0 = t4 * JT;

    // ---- stage z-tile f32 -> bf16 LDS (swizzled) ----
#pragma unroll
    for (int q = 0; q < 4; ++q) {
      int chunk = q * 512 + tid;                  // 0..2047
      int row = chunk >> 4, c8 = chunk & 15;
      const float4* zp = (const float4*)(zbase + (size_t)(j0 + row) * CZ + c8 * 8);
      float4 a4 = zp[0], b4 = zp[1];
      bf16x8 p;
      p[0] = (short)f2bf(a4.x); p[1] = (short)f2bf(a4.y);
      p[2] = (short)f2bf(a4.z); p[3] = (short)f2bf(a4.w);
      p[4] = (short)f2bf(b4.x); p[5] = (short)f2bf(b4.y);
      p[6] = (short)f2bf(b4.z); p[7] = (short)f2bf(b4.w);
      *(bf16x8*)&zt[row * CZ + ((c8 ^ (row & 7)) << 3)] = p;
    }
    __syncthreads();                               // (A) zt ready

    // ---- logits MFMA: wave w owns j-rows w*16..w*16+15 of this tile ----
    f32x4 dl = {0.f, 0.f, 0.f, 0.f};
    int jrow = w * 16 + cl;                        // A row: tile-local j
    int jg = j0 + jrow;                            // global j
#pragma unroll
    for (int kk = 0; kk < 4; ++kk) {
      int c8 = kk * 4 + lk;
      bf16x8 a = *(const bf16x8*)&zt[jrow * CZ + ((c8 ^ (jrow & 7)) << 3)];
      bf16x8 b = *(const bf16x8*)&wbf[(kk * 64 + l) * 8];
      dl = __builtin_amdgcn_mfma_f32_16x16x32_bf16(a, b, dl, 0, 0, 0);
    }
#pragma unroll
    for (int hp = 0; hp < Hh; ++hp) {
      bf16x8 a = *(const bf16x8*)&ekb[((size_t)jg * Hh + hp) * 32 + lk * 8];
      bf16x8 bq = *(const bf16x8*)&eqb[((size_t)i * Hh + hp) * 32 + lk * 8];
      bf16x8 b = (cl == hp) ? bq : zer;
      dl = __builtin_amdgcn_mfma_f32_16x16x32_bf16(a, b, dl, 0, 0, 0);
    }

    // lane holds logits for head cl, j = j0 + w*16 + lk*4 + r  (mq dropped: j-const)
    float v[4];
    int jb = j0 + w * 16 + lk * 4;
    if (cl < Hh) {
#pragma unroll
      for (int r = 0; r < 4; ++r) v[r] = W_L * (dl[r] + mk[(jb + r) * Hh + cl]);
    } else {
#pragma unroll
      for (int r = 0; r < 4; ++r) v[r] = -1e30f;
    }

    // ---- online max ----
    float mx = fmaxf(fmaxf(v[0], v[1]), fmaxf(v[2], v[3]));
    mx = fmaxf(mx, __shfl_xor(mx, 16));
    mx = fmaxf(mx, __shfl_xor(mx, 32));
    if (lk == 0) red[w][cl] = mx;
    __syncthreads();                               // (B)
    if (tid < 16) {
      float tm = red[0][tid];
#pragma unroll
      for (int ww = 1; ww < 8; ++ww) tm = fmaxf(tm, red[ww][tid]);
      float mnew = fmaxf(m_run, tm);
      scbc[tid] = __expf(m_run - mnew);
      m_run = mnew;
      mbc[tid] = mnew;
    }
    __syncthreads();                               // (C)

    // ---- P = exp(v - m); pbuf write; partial sums; acc rescale ----
    float mh = mbc[cl];
    float ps = 0.f;
#pragma unroll
    for (int r = 0; r < 4; ++r) {
      float pv = __expf(v[r] - mh);
      ushort_t pb = f2bf(pv);
      pbuf[cl * 136 + w * 16 + lk * 4 + r] = pb;
      ps += bf2f(pb);                              // sum of rounded values
    }
    ps += __shfl_xor(ps, 16);
    ps += __shfl_xor(ps, 32);
    if (lk == 0) red[w][cl] = ps;
    float sc0 = scbc[lk * 4 + 0], sc1 = scbc[lk * 4 + 1];
    float sc2 = scbc[lk * 4 + 2], sc3 = scbc[lk * 4 + 3];
#pragma unroll
    for (int n = 0; n < 5; ++n) {
      acc[n][0] *= sc0; acc[n][1] *= sc1; acc[n][2] *= sc2; acc[n][3] *= sc3;
    }
    __syncthreads();                               // (D) pbuf + red ready

    if (tid < 16) {
      float ts = 0.f;
#pragma unroll
      for (int ww = 0; ww < 8; ++ww) ts += red[ww][tid];
      l_run = l_run * scbc[tid] + ts;
    }

    // ---- attend MFMAs: out[h][col] += P[h][j] * V[j][col] ----
#pragma unroll
    for (int kk = 0; kk < 4; ++kk) {
      bf16x8 af = *(const bf16x8*)&pbuf[cl * 136 + kk * 32 + lk * 8];
      int jk = j0 + kk * 32 + lk * 8;
#pragma unroll
      for (int n = 0; n < 5; ++n) {
        int t = w + n * 8;
        if (t < 38) {
          bf16x8 bf;
          if (t < 8) {                             // o_pair: transposed zt read
            int c = t * 16 + cl;
#pragma unroll
            for (int e = 0; e < 8; ++e) {
              int rr = kk * 32 + lk * 8 + e;
              bf[e] = (short)zt[rr * CZ + ((((c >> 3) ^ (rr & 7)) << 3) | (c & 7))];
            }
          } else if (t < 20) {                     // o_sc
            bf = *(const bf16x8*)(vT + (size_t)((t - 8) * 16 + cl) * Nn + jk);
          } else {                                 // o_pt
            bf = *(const bf16x8*)(vpT + (size_t)((t - 20) * 16 + cl) * Nn + jk);
          }
          acc[n] = __builtin_amdgcn_mfma_f32_16x16x32_bf16(af, bf, acc[n], 0, 0, 0);
        }
      }
    }
    __syncthreads();                               // (E) zt/pbuf consumed
  }

  // ---- finalize: divide by l ----
  if (tid < 16) linv[tid] = (tid < Hh) ? 1.f / l_run : 0.f;
  __syncthreads();
  float rl0 = linv[lk * 4 + 0], rl1 = linv[lk * 4 + 1];
  float rl2 = linv[lk * 4 + 2], rl3 = linv[lk * 4 + 3];
#pragma unroll
  for (int n = 0; n < 5; ++n) {
    acc[n][0] *= rl0; acc[n][1] *= rl1; acc[n][2] *= rl2; acc[n][3] *= rl3;
  }

  // ---- epilogue: D row = lk*4+r (head), D col = cl ----
#pragma unroll
  for (int n = 0; n < 5; ++n) {
    int t = w + n * 8;
    if (t < 38) {
      if (t < 8) {
        int c = t * 16 + cl;
#pragma unroll
        for (int r = 0; r < 4; ++r) {
          int h = lk * 4 + r;
          if (h < Hh) Fi[h * CZ + c] = acc[n][r];
        }
      } else if (t < 20) {
        int h = t - 8;
        if (lk == (h >> 2)) Fi[1536 + h * CH + cl] = acc[n][h & 3];
      } else {
        int cp = (t - 20) * 16 + cl;
        int h = cp / 24;
        if (lk == (h >> 2)) optg[cp] = acc[n][h & 3];
      }
    }
  }
  __syncthreads();

  if (tid < 96) {
    int h = tid >> 3, p = tid & 7;
    float g0 = optg[h * 24 + p * 3 + 0] - trans[i * 3 + 0];
    float g1 = optg[h * 24 + p * 3 + 1] - trans[i * 3 + 1];
    float g2 = optg[h * 24 + p * 3 + 2] - trans[i * 3 + 2];
    const float* R = rot + i * 9;
    float ss = 0.f;
#pragma unroll
    for (int nn2 = 0; nn2 < 3; ++nn2) {
      float o = R[nn2] * g0 + R[3 + nn2] * g1 + R[6 + nn2] * g2;   // R^T (g - t)
      Fi[1728 + h * 24 + p * 3 + nn2] = o;
      ss += o * o;
    }
    Fi[2016 + h * 8 + p] = sqrtf(ss + 1e-12f);
  }
}

// ============ K5a: out partials  part[fs][i][o] = feat[f-slice] @ Wf ========
__global__ __launch_bounds__(384) void k_out_partial(
    const float* __restrict__ feat, const float* __restrict__ Wf,
    float* __restrict__ part) {
  int fs = blockIdx.x;                     // 0..7 (f-slice of 264)
  int i0 = blockIdx.y * 8;
  int o = threadIdx.x;                     // 0..383
  float acc[8];
#pragma unroll
  for (int ii = 0; ii < 8; ++ii) acc[ii] = 0.f;
  int f0 = fs * 264;
#pragma unroll 4
  for (int f = f0; f < f0 + 264; ++f) {
    float w = Wf[(size_t)f * CS + o];
#pragma unroll
    for (int ii = 0; ii < 8; ++ii) acc[ii] += w * feat[(size_t)(i0 + ii) * FIN + f];
  }
#pragma unroll
  for (int ii = 0; ii < 8; ++ii)
    part[((size_t)fs * Nn + i0 + ii) * CS + o] = acc[ii];
}

// ============ K5b: reduce partials + bias -> out ============================
__global__ __launch_bounds__(256) void k_out_reduce(
    const float* __restrict__ part, const float* __restrict__ bf,
    float* __restrict__ out) {
  int idx = blockIdx.x * 256 + threadIdx.x;        // < 512*384
  float s = bf[idx % CS];
#pragma unroll
  for (int fs = 0; fs < 8; ++fs) s += part[(size_t)fs * (Nn * CS) + idx];
  out[idx] = s;
}

// ============================ launcher ======================================
extern "C" void kernel_launch(void* const* d_in, const int* in_sizes, int n_in,
                              void* d_out, int out_size, void* d_ws, size_t ws_size,
                              hipStream_t stream) {
  const float* s_i   = (const float*)d_in[0];
  const float* z_ij  = (const float*)d_in[1];
  const float* rot   = (const float*)d_in[2];
  const float* trans = (const float*)d_in[3];
  const float* Wq    = (const float*)d_in[4];
  const float* Wk    = (const float*)d_in[5];
  const float* Wv    = (const float*)d_in[6];
  const float* Wqp   = (const float*)d_in[7];
  const float* Wkp   = (const float*)d_in[8];
  const float* Wvp   = (const float*)d_in[9];
  const float* Wb    = (const float*)d_in[10];
  const float* gamma = (const float*)d_in[11];
  const float* Wf    = (const float*)d_in[12];
  const float* bf    = (const float*)d_in[13];
  float* out = (float*)d_out;

  float* w = (float*)d_ws;
  float*    P    = w + OFF_P;
  float*    mq   = w + OFF_MQ;
  float*    mk   = w + OFF_MK;
  ushort_t* vT   = (ushort_t*)(w + OFF_VT);
  ushort_t* vpT  = (ushort_t*)(w + OFF_VPT);
  float*    feat = w + OFF_FEAT;
  float*    lg   = w + OFF_LOG;     // K5 partials
  ushort_t* ekb  = (ushort_t*)(w + OFF_EKB);
  ushort_t* eqb  = (ushort_t*)(w + OFF_EQB);
  ushort_t* wbf  = (ushort_t*)(w + OFF_WBF);

  k_proj<<<dim3(3, 64), 384, 0, stream>>>(s_i, Wq, Wk, Wv, Wqp, Wkp, Wvp, P);
  k_prep<<<96, 64, 0, stream>>>(P, rot, trans, gamma, eqb, ekb, mq, mk, vT, vpT);
  k_wbfrag<<<1, 256, 0, stream>>>(Wb, wbf);
  k_fused<<<512, 512, 0, stream>>>(z_ij, eqb, ekb, wbf, mk, vT, vpT, rot, trans, feat);
  k_out_partial<<<dim3(8, 64), 384, 0, stream>>>(feat, Wf, lg);
  k_out_reduce<<<768, 256, 0, stream>>>(lg, bf, out);
}